// Round 7
// baseline (381.628 us; speedup 1.0000x reference)
//
#include <hip/hip_runtime.h>

// out[n, k*D + d] = M[k, n, d]  with K=4, N=500000, D=128, fp32.
// Wave w owns output rows 2p, 2p+1 (p = grid-stride wave index).
// READ  (1KB dense/instr):  r_k[lane] = in4[k*PLANE4 + p*64 + lane]
//       -> lane l holds (plane k, row 2p+(l>>5), col l&31)
// SWAP  v_permlane32_swap_b32 (vdst.hi <-> vsrc.lo), per dword:
//       swap(r0,r1): r0 = [r0.lo|r1.lo] = row 2p,  planes{0,1}
//                    r1 = [r0.hi|r1.hi] = row 2p+1, planes{0,1}
//       swap(r2,r3): same for planes {2,3}
// WRITE (1KB dense/instr): 4 NT stores = contiguous 4KB output span.
// Both sides now structurally identical to a pure linear copy.

typedef float v4f __attribute__((ext_vector_type(4)));

static constexpr long long N = 500000;              // even
static constexpr long long ROW4   = 32;             // v4f per (k,n) row
static constexpr long long PLANE4 = N * ROW4;       // v4f per k-plane
static constexpr long long NPAIR  = N / 2;

__global__ void msgcat_kernel(const v4f* __restrict__ in, v4f* __restrict__ out) {
    const int lane        = threadIdx.x & 63;
    const int waveInBlock = threadIdx.x >> 6;
    const int wavesPerBlk = blockDim.x >> 6;
    const long long totalWaves = (long long)gridDim.x * wavesPerBlk;

    for (long long p = (long long)blockIdx.x * wavesPerBlk + waveInBlock;
         p < NPAIR; p += totalWaves) {
        const long long rbase = p * 64 + lane;      // rows 2p,2p+1 of a plane
        v4f r0 = __builtin_nontemporal_load(&in[0 * PLANE4 + rbase]);
        v4f r1 = __builtin_nontemporal_load(&in[1 * PLANE4 + rbase]);
        v4f r2 = __builtin_nontemporal_load(&in[2 * PLANE4 + rbase]);
        v4f r3 = __builtin_nontemporal_load(&in[3 * PLANE4 + rbase]);
        #pragma unroll
        for (int i = 0; i < 4; ++i) {
            float a0 = r0[i], b0 = r1[i];
            asm volatile("v_permlane32_swap_b32 %0, %1" : "+v"(a0), "+v"(b0));
            r0[i] = a0; r1[i] = b0;
            float a1 = r2[i], b1 = r3[i];
            asm volatile("v_permlane32_swap_b32 %0, %1" : "+v"(a1), "+v"(b1));
            r2[i] = a1; r3[i] = b1;
        }
        const long long o = p * 256 + lane;         // out4 base of row 2p
        __builtin_nontemporal_store(r0, &out[o]);           // row 2p,   planes 0|1
        __builtin_nontemporal_store(r2, &out[o + 64]);      // row 2p,   planes 2|3
        __builtin_nontemporal_store(r1, &out[o + 128]);     // row 2p+1, planes 0|1
        __builtin_nontemporal_store(r3, &out[o + 192]);     // row 2p+1, planes 2|3
    }
}

extern "C" void kernel_launch(void* const* d_in, const int* in_sizes, int n_in,
                              void* d_out, int out_size, void* d_ws, size_t ws_size,
                              hipStream_t stream) {
    const v4f* in  = (const v4f*)d_in[0];
    v4f*       out = (v4f*)d_out;
    const int block = 256;                 // 4 waves/block
    const int grid  = 2048;                // 8 blocks/CU on 256 CUs
    msgcat_kernel<<<grid, block, 0, stream>>>(in, out);
}

// Round 8
// 372.966 us; speedup vs baseline: 1.0232x; 1.0232x over previous
//
#include <hip/hip_runtime.h>

// out[n, k*D + d] = M[k, n, d]  with K=4, N=500000, D=128, fp32.
// Wave w owns output rows 2p, 2p+1 (p = grid-stride wave index).
// READ  (1KB dense/instr):  r_k[lane] = in4[k*PLANE4 + p*64 + lane]
// SWAP  v_permlane32_swap_b32 (NON-volatile asm: ordered only by data deps,
//       so the compiler can pipeline pair{r0,r1} swap+store under the
//       {r2,r3} loads and overlap next-iteration loads).
// WRITE (1KB dense/instr): 4 NT stores = contiguous 4KB output span.

typedef float v4f __attribute__((ext_vector_type(4)));

static constexpr long long N = 500000;              // even
static constexpr long long ROW4   = 32;             // v4f per (k,n) row
static constexpr long long PLANE4 = N * ROW4;       // v4f per k-plane
static constexpr long long NPAIR  = N / 2;

__global__ void msgcat_kernel(const v4f* __restrict__ in, v4f* __restrict__ out) {
    const int lane        = threadIdx.x & 63;
    const int waveInBlock = threadIdx.x >> 6;
    const int wavesPerBlk = blockDim.x >> 6;
    const long long totalWaves = (long long)gridDim.x * wavesPerBlk;

    for (long long p = (long long)blockIdx.x * wavesPerBlk + waveInBlock;
         p < NPAIR; p += totalWaves) {
        const long long rbase = p * 64 + lane;      // rows 2p,2p+1 of a plane
        v4f r0 = __builtin_nontemporal_load(&in[0 * PLANE4 + rbase]);
        v4f r1 = __builtin_nontemporal_load(&in[1 * PLANE4 + rbase]);
        v4f r2 = __builtin_nontemporal_load(&in[2 * PLANE4 + rbase]);
        v4f r3 = __builtin_nontemporal_load(&in[3 * PLANE4 + rbase]);
        #pragma unroll
        for (int i = 0; i < 4; ++i) {
            float a0 = r0[i], b0 = r1[i];
            asm("v_permlane32_swap_b32 %0, %1" : "+v"(a0), "+v"(b0));
            r0[i] = a0; r1[i] = b0;
        }
        #pragma unroll
        for (int i = 0; i < 4; ++i) {
            float a1 = r2[i], b1 = r3[i];
            asm("v_permlane32_swap_b32 %0, %1" : "+v"(a1), "+v"(b1));
            r2[i] = a1; r3[i] = b1;
        }
        const long long o = p * 256 + lane;         // out4 base of row 2p
        __builtin_nontemporal_store(r0, &out[o]);           // row 2p,   planes 0|1
        __builtin_nontemporal_store(r2, &out[o + 64]);      // row 2p,   planes 2|3
        __builtin_nontemporal_store(r1, &out[o + 128]);     // row 2p+1, planes 0|1
        __builtin_nontemporal_store(r3, &out[o + 192]);     // row 2p+1, planes 2|3
    }
}

extern "C" void kernel_launch(void* const* d_in, const int* in_sizes, int n_in,
                              void* d_out, int out_size, void* d_ws, size_t ws_size,
                              hipStream_t stream) {
    const v4f* in  = (const v4f*)d_in[0];
    v4f*       out = (v4f*)d_out;
    const int block = 256;                 // 4 waves/block
    const int grid  = 2048;                // 8 blocks/CU on 256 CUs
    msgcat_kernel<<<grid, block, 0, stream>>>(in, out);
}

// Round 9
// 369.523 us; speedup vs baseline: 1.0328x; 1.0093x over previous
//
#include <hip/hip_runtime.h>

// out[n, k*D + d] = M[k, n, d]  with K=4, N=500000, D=128, fp32.
// Wave owns 4 ADJACENT output rows 4q..4q+3 (two R5-style pairs).
//   lane l:  k0 = l>>5 (0/1), c = l&31 (float4 column)
//   8 loads issued back-to-back (8 in flight), then 8 NT stores covering
//   a contiguous 8KB output span. Addressing identical to R5, just deeper.

typedef float v4f __attribute__((ext_vector_type(4)));

static constexpr long long N = 500000;              // divisible by 4
static constexpr long long ROW4   = 32;             // v4f per (k,n) row
static constexpr long long PLANE4 = N * ROW4;       // v4f per k-plane
static constexpr long long NQUAD  = N / 4;          // 125000 row-quads

__global__ void msgcat_kernel(const v4f* __restrict__ in, v4f* __restrict__ out) {
    const int lane        = threadIdx.x & 63;
    const int waveInBlock = threadIdx.x >> 6;
    const int wavesPerBlk = blockDim.x >> 6;
    const long long totalWaves = (long long)gridDim.x * wavesPerBlk;

    const int k0 = lane >> 5;        // 0 or 1
    const int c  = lane & 31;        // v4f column within 128-float row

    const long long pA = (long long)k0 * PLANE4 + c;        // planes 0/1
    const long long pB = (long long)(k0 + 2) * PLANE4 + c;  // planes 2/3

    const long long q0 = (long long)blockIdx.x * wavesPerBlk + waveInBlock;
    // pointer-increment form: per-iteration input advance = 4 rows * ROW4,
    // output advance = 4 rows * 128 v4f
    const v4f* inA = in + pA + q0 * (4 * ROW4);
    const v4f* inB = in + pB + q0 * (4 * ROW4);
    v4f*       op  = out + q0 * 512 + lane;
    const long long stepIn  = totalWaves * 4 * ROW4;
    const long long stepOut = totalWaves * 512;

    for (long long q = q0; q < NQUAD; q += totalWaves) {
        v4f a0 = __builtin_nontemporal_load(inA + 0 * ROW4);
        v4f a1 = __builtin_nontemporal_load(inA + 1 * ROW4);
        v4f a2 = __builtin_nontemporal_load(inA + 2 * ROW4);
        v4f a3 = __builtin_nontemporal_load(inA + 3 * ROW4);
        v4f b0 = __builtin_nontemporal_load(inB + 0 * ROW4);
        v4f b1 = __builtin_nontemporal_load(inB + 1 * ROW4);
        v4f b2 = __builtin_nontemporal_load(inB + 2 * ROW4);
        v4f b3 = __builtin_nontemporal_load(inB + 3 * ROW4);
        __builtin_nontemporal_store(a0, op + 0 * 128);        // row 4q,   planes 0|1
        __builtin_nontemporal_store(b0, op + 0 * 128 + 64);   // row 4q,   planes 2|3
        __builtin_nontemporal_store(a1, op + 1 * 128);
        __builtin_nontemporal_store(b1, op + 1 * 128 + 64);
        __builtin_nontemporal_store(a2, op + 2 * 128);
        __builtin_nontemporal_store(b2, op + 2 * 128 + 64);
        __builtin_nontemporal_store(a3, op + 3 * 128);
        __builtin_nontemporal_store(b3, op + 3 * 128 + 64);
        inA += stepIn; inB += stepIn; op += stepOut;
    }
}

extern "C" void kernel_launch(void* const* d_in, const int* in_sizes, int n_in,
                              void* d_out, int out_size, void* d_ws, size_t ws_size,
                              hipStream_t stream) {
    const v4f* in  = (const v4f*)d_in[0];
    v4f*       out = (v4f*)d_out;
    const int block = 256;                 // 4 waves/block
    const int grid  = 2048;                // 8 blocks/CU on 256 CUs
    msgcat_kernel<<<grid, block, 0, stream>>>(in, out);
}